// Round 1
// baseline (300.632 us; speedup 1.0000x reference)
//
#include <hip/hip_runtime.h>
#include <stdint.h>

// Problem constants (B=4, C=256, C8=32, H=W=64, N=4096)
#define NB 4
#define NC 256
#define NC8 32
#define NN 4096

typedef __attribute__((ext_vector_type(8))) short bf16x8;
typedef __attribute__((ext_vector_type(4))) float f32x4;
typedef __attribute__((ext_vector_type(8))) unsigned short u16x8;
typedef __attribute__((ext_vector_type(4))) unsigned short u16x4;

#define MFMA16(a, b, c) __builtin_amdgcn_mfma_f32_16x16x32_bf16((a), (b), (c), 0, 0, 0)

__device__ __forceinline__ unsigned short bf16_rne(float f) {
    unsigned int u = __builtin_bit_cast(unsigned int, f);
    u += 0x7fffu + ((u >> 16) & 1u);
    return (unsigned short)(u >> 16);
}
__device__ __forceinline__ float bf16_to_f(unsigned short h) {
    return __builtin_bit_cast(float, (unsigned int)h << 16);
}

template <int CTRL>
__device__ __forceinline__ float dpp_mov_f(float v) {
    return __builtin_bit_cast(float,
        __builtin_amdgcn_update_dpp(0, __builtin_bit_cast(int, v), CTRL, 0xf, 0xf, false));
}
// reduce across the 16-lane row (all lanes end with the result)
__device__ __forceinline__ float rowmax16(float v) {
    v = fmaxf(v, dpp_mov_f<0x128>(v));  // row_ror:8
    v = fmaxf(v, dpp_mov_f<0x124>(v));  // row_ror:4
    v = fmaxf(v, dpp_mov_f<0x122>(v));  // row_ror:2
    v = fmaxf(v, dpp_mov_f<0x121>(v));  // row_ror:1
    return v;
}
__device__ __forceinline__ float rowsum16(float v) {
    v += dpp_mov_f<0x128>(v);
    v += dpp_mov_f<0x124>(v);
    v += dpp_mov_f<0x122>(v);
    v += dpp_mov_f<0x121>(v);
    return v;
}

__device__ __forceinline__ void async16(const void* g, void* l) {
    __builtin_amdgcn_global_load_lds(
        (const __attribute__((address_space(1))) unsigned int*)g,
        (__attribute__((address_space(3))) unsigned int*)l, 16, 0, 0);
}

// ---------------------------------------------------------------------------
// Projection kernel: q,k (fp32 -> bf16 hi/lo split) and v (bf16), BN folded.
// q_hi/q_lo/k_hi/k_lo layout: [B][N][32] bf16 ; v layout: [B][256][N] bf16.
// Grid: 512 blocks x 256 threads; block handles 32 spatial positions.
// ---------------------------------------------------------------------------
__global__ __launch_bounds__(256) void proj_kernel(
    const float* __restrict__ x,
    const float* __restrict__ wq,
    const float* __restrict__ qg, const float* __restrict__ qb,
    const float* __restrict__ qm, const float* __restrict__ qv,
    const float* __restrict__ wk,
    const float* __restrict__ kg, const float* __restrict__ kb,
    const float* __restrict__ km, const float* __restrict__ kv,
    const float* __restrict__ wv,
    const float* __restrict__ vg, const float* __restrict__ vb,
    const float* __restrict__ vm, const float* __restrict__ vv,
    unsigned short* __restrict__ qhi, unsigned short* __restrict__ qlo,
    unsigned short* __restrict__ khi, unsigned short* __restrict__ klo,
    unsigned short* __restrict__ vws)
{
    __shared__ float xt[NC * 36 + 8];   // [c][36] stride keeps float4 aligned, spreads banks
    const int t = threadIdx.x;
    const int blk = blockIdx.x;
    const int b = blk >> 7;                 // 128 blocks per batch
    const int n0 = (blk & 127) << 5;        // 32 positions
    const float* xb = x + ((size_t)b << 20);  // b*C*N

    for (int idx = t; idx < NC * 32; idx += 256) {
        int c = idx >> 5, j = idx & 31;
        xt[c * 36 + j] = xb[((size_t)c << 12) + n0 + j];
    }
    __syncthreads();

    // ---- q / k : thread = (p = t&31, og = t>>5); og 0-3 -> q rows o0..o0+7, og 4-7 -> k
    {
        const int p = t & 31;
        const int og = t >> 5;
        const bool is_k = og >= 4;
        const int o0 = (og & 3) << 3;
        const float* w = is_k ? wk : wq;
        float acc[8];
#pragma unroll
        for (int o = 0; o < 8; ++o) acc[o] = 0.f;
        for (int c4 = 0; c4 < NC; c4 += 4) {
            float x0 = xt[(c4 + 0) * 36 + p];
            float x1 = xt[(c4 + 1) * 36 + p];
            float x2 = xt[(c4 + 2) * 36 + p];
            float x3 = xt[(c4 + 3) * 36 + p];
#pragma unroll
            for (int o = 0; o < 8; ++o) {
                const float4 w4 = *(const float4*)&w[(o0 + o) * NC + c4];
                acc[o] += w4.x * x0 + w4.y * x1 + w4.z * x2 + w4.w * x3;
            }
        }
        const float* G = is_k ? kg : qg;
        const float* Bb = is_k ? kb : qb;
        const float* M = is_k ? km : qm;
        const float* V = is_k ? kv : qv;
        u16x8 hv, lv;
#pragma unroll
        for (int o = 0; o < 8; ++o) {
            int oo = o0 + o;
            float sc = G[oo] / sqrtf(V[oo] + 1e-5f);
            float val = acc[o] * sc + (Bb[oo] - M[oo] * sc);
            unsigned short h = bf16_rne(val);
            hv[o] = h;
            lv[o] = bf16_rne(val - bf16_to_f(h));
        }
        size_t base = ((size_t)(b << 12) + n0 + p) * 32 + o0;
        *(u16x8*)&(is_k ? khi : qhi)[base] = hv;
        *(u16x8*)&(is_k ? klo : qlo)[base] = lv;
    }

    // ---- v : thread = (p4 = (t&7)*4, og = t>>3); outputs o0 = og*8 .. +7, 4 positions
    {
        const int p4 = (t & 7) << 2;
        const int og = t >> 3;
        const int o0 = og << 3;
        float acc[4][8];
#pragma unroll
        for (int pp = 0; pp < 4; ++pp)
#pragma unroll
            for (int o = 0; o < 8; ++o) acc[pp][o] = 0.f;
        for (int c4 = 0; c4 < NC; c4 += 4) {
            float4 xv0 = *(const float4*)&xt[(c4 + 0) * 36 + p4];
            float4 xv1 = *(const float4*)&xt[(c4 + 1) * 36 + p4];
            float4 xv2 = *(const float4*)&xt[(c4 + 2) * 36 + p4];
            float4 xv3 = *(const float4*)&xt[(c4 + 3) * 36 + p4];
#pragma unroll
            for (int o = 0; o < 8; ++o) {
                const float4 w4 = *(const float4*)&wv[(o0 + o) * NC + c4];
                acc[0][o] += w4.x * xv0.x + w4.y * xv1.x + w4.z * xv2.x + w4.w * xv3.x;
                acc[1][o] += w4.x * xv0.y + w4.y * xv1.y + w4.z * xv2.y + w4.w * xv3.y;
                acc[2][o] += w4.x * xv0.z + w4.y * xv1.z + w4.z * xv2.z + w4.w * xv3.z;
                acc[3][o] += w4.x * xv0.w + w4.y * xv1.w + w4.z * xv2.w + w4.w * xv3.w;
            }
        }
#pragma unroll
        for (int o = 0; o < 8; ++o) {
            int oo = o0 + o;
            float sc = vg[oo] / sqrtf(vv[oo] + 1e-5f);
            float sh = vb[oo] - vm[oo] * sc;
            u16x4 st;
#pragma unroll
            for (int pp = 0; pp < 4; ++pp) st[pp] = bf16_rne(acc[pp][o] * sc + sh);
            *(u16x4*)&vws[((size_t)(b * NC + oo) << 12) + n0 + p4] = st;
        }
    }
}

// ---------------------------------------------------------------------------
// Flash attention kernel. Grid: 256 blocks (blk&3 = batch, blk>>2 = 64-row
// i-tile) x 4 waves. Wave (wi,wc) owns rows i0+wi*32..+31, cols wc*128..+127.
// LDS: double-buffered {K_hi 2K | K_lo 2K | V 16K} + per-wave P (2.5K),
// epilogue reuses LDS as [256][68] fp32 transpose buffer.
// ---------------------------------------------------------------------------
__global__ __launch_bounds__(256) void attn_kernel(
    const float* __restrict__ x, const float* __restrict__ gamma_p,
    const unsigned short* __restrict__ qhi, const unsigned short* __restrict__ qlo,
    const unsigned short* __restrict__ khi, const unsigned short* __restrict__ klo,
    const unsigned short* __restrict__ vws,
    float* __restrict__ out)
{
    __shared__ __align__(16) char smem[69632];
    const int t = threadIdx.x;
    const int blk = blockIdx.x;
    const int b = blk & 3;
    const int i0 = (blk >> 2) << 6;
    const int w = t >> 6, lane = t & 63;
    const int g = lane >> 4, r = lane & 15;
    const int wi = w >> 1, wc = w & 1;

    const size_t bN32 = (size_t)b * (NN * 32);
    const unsigned short* kh_g = khi + bN32;
    const unsigned short* kl_g = klo + bN32;
    const unsigned short* v_g = vws + (size_t)b * (NC * NN);

    // Q fragments (A-operand): lane holds row i=(l&15), k = (l>>4)*8..+7
    bf16x8 qh[2], ql[2];
#pragma unroll
    for (int fi = 0; fi < 2; ++fi) {
        int i = i0 + wi * 32 + fi * 16 + r;
        size_t off = bN32 + (size_t)i * 32 + g * 8;
        qh[fi] = *(const bf16x8*)&qhi[off];
        ql[fi] = *(const bf16x8*)&qlo[off];
    }

    f32x4 acc[2][8];
#pragma unroll
    for (int fi = 0; fi < 2; ++fi)
#pragma unroll
        for (int fc = 0; fc < 8; ++fc) acc[fi][fc] = (f32x4){0.f, 0.f, 0.f, 0.f};
    float m_run[8], l_part[8];
#pragma unroll
    for (int i = 0; i < 8; ++i) { m_run[i] = -3.0e38f; l_part[i] = 0.f; }

    // stage one 32-j tile (20 chunks of 1KB) into buffer buf
    auto stage = [&](int jt, int buf) {
        char* base = smem + buf * 20480;
        const int j0 = jt << 5;
        for (int cidx = w; cidx < 20; cidx += 4) {
            const unsigned short* gs;
            if (cidx < 4) {
                gs = (cidx < 2 ? kh_g : kl_g) + (size_t)j0 * 32 + ((cidx & 1) << 9) + lane * 8;
            } else {
                int kk = cidx - 4;
                int c = (kk << 4) + (lane >> 2);
                gs = v_g + ((size_t)c << 12) + j0 + ((lane & 3) << 3);
            }
            async16(gs, base + cidx * 1024);
        }
    };

    stage(0, 0);
    __syncthreads();

    for (int jt = 0; jt < NN / 32; ++jt) {
        const int buf = jt & 1;
        if (jt < NN / 32 - 1) stage(jt + 1, buf ^ 1);

        const char* base = smem + buf * 20480;
        const unsigned short* Kh = (const unsigned short*)(base);
        const unsigned short* Kl = (const unsigned short*)(base + 2048);
        const unsigned short* Vl = (const unsigned short*)(base + 4096);

        // ---- S = Q K^T (hi/lo split, fp32 acc) ----
        bf16x8 kfh[2], kfl[2];
#pragma unroll
        for (int fj = 0; fj < 2; ++fj) {
            int off = ((fj * 16 + r) << 5) + g * 8;  // K_lds[j][c], 64B rows
            kfh[fj] = *(const bf16x8*)&Kh[off];
            kfl[fj] = *(const bf16x8*)&Kl[off];
        }
        f32x4 s[2][2];
#pragma unroll
        for (int fi = 0; fi < 2; ++fi)
#pragma unroll
            for (int fj = 0; fj < 2; ++fj) {
                f32x4 z = (f32x4){0.f, 0.f, 0.f, 0.f};
                z = MFMA16(qh[fi], kfl[fj], z);
                z = MFMA16(ql[fi], kfh[fj], z);
                z = MFMA16(qh[fi], kfh[fj], z);
                s[fi][fj] = z;
            }

        // ---- online softmax (rows replicated across each 16-lane group) ----
        float tm[8];
#pragma unroll
        for (int fi = 0; fi < 2; ++fi)
#pragma unroll
            for (int e = 0; e < 4; ++e)
                tm[fi * 4 + e] = fmaxf(s[fi][0][e], s[fi][1][e]);
#pragma unroll
        for (int i = 0; i < 8; ++i) tm[i] = rowmax16(tm[i]);

        bool okf = true;
#pragma unroll
        for (int i = 0; i < 8; ++i) okf = okf && (tm[i] <= m_run[i] + 8.0f);
        if (!__all(okf)) {
            float rs[8];
#pragma unroll
            for (int i = 0; i < 8; ++i) {
                float nm = fmaxf(m_run[i], tm[i]);
                rs[i] = __expf(m_run[i] - nm);
                m_run[i] = nm;
                l_part[i] *= rs[i];
            }
#pragma unroll
            for (int fi = 0; fi < 2; ++fi)
#pragma unroll
                for (int fc = 0; fc < 8; ++fc)
#pragma unroll
                    for (int e = 0; e < 4; ++e) acc[fi][fc][e] *= rs[fi * 4 + e];
        }

        float p[2][2][4];
#pragma unroll
        for (int fi = 0; fi < 2; ++fi)
#pragma unroll
            for (int fj = 0; fj < 2; ++fj)
#pragma unroll
                for (int e = 0; e < 4; ++e)
                    p[fi][fj][e] = __expf(s[fi][fj][e] - m_run[fi * 4 + e]);
#pragma unroll
        for (int fi = 0; fi < 2; ++fi)
#pragma unroll
            for (int e = 0; e < 4; ++e)
                l_part[fi * 4 + e] += p[fi][0][e] + p[fi][1][e];

        // ---- P: D-frag -> bf16 -> per-wave LDS (row stride 40 ushorts) ----
        unsigned short* P = (unsigned short*)(smem + 40960 + w * 2560);
#pragma unroll
        for (int fi = 0; fi < 2; ++fi)
#pragma unroll
            for (int fj = 0; fj < 2; ++fj)
#pragma unroll
                for (int e = 0; e < 4; ++e)
                    P[(fi * 16 + g * 4 + e) * 40 + fj * 16 + r] = bf16_rne(p[fi][fj][e]);
        asm volatile("s_waitcnt lgkmcnt(0)" ::: "memory");
        __builtin_amdgcn_sched_barrier(0);

        // ---- PV: acc += P[16x32] * V[32x16] ----
        bf16x8 pa[2];
#pragma unroll
        for (int fi = 0; fi < 2; ++fi)
            pa[fi] = *(const bf16x8*)&P[(fi * 16 + r) * 40 + g * 8];
#pragma unroll
        for (int fc = 0; fc < 8; ++fc) {
            bf16x8 vbf = *(const bf16x8*)&Vl[((wc * 128 + fc * 16 + r) << 5) + g * 8];
            acc[0][fc] = MFMA16(pa[0], vbf, acc[0][fc]);
            acc[1][fc] = MFMA16(pa[1], vbf, acc[1][fc]);
        }
        __syncthreads();  // drains stage(jt+1) vmcnt + protects buffer swap
    }

    // ---- epilogue: out = gamma * acc/l + x, transposed through LDS ----
    const float gm = gamma_p[0];
    float linv[8];
#pragma unroll
    for (int i = 0; i < 8; ++i) linv[i] = gm / rowsum16(l_part[i]);

    __syncthreads();
    float* out_t = (float*)smem;  // [256][68]
#pragma unroll
    for (int fi = 0; fi < 2; ++fi)
#pragma unroll
        for (int fc = 0; fc < 8; ++fc)
#pragma unroll
            for (int e = 0; e < 4; ++e) {
                int il = wi * 32 + fi * 16 + g * 4 + e;
                int c = wc * 128 + fc * 16 + r;
                out_t[c * 68 + il] = acc[fi][fc][e] * linv[fi * 4 + e];
            }
    __syncthreads();

    const float* xb = x + ((size_t)b << 20);
    float* ob = out + ((size_t)b << 20);
#pragma unroll
    for (int it = 0; it < 16; ++it) {
        int c = (t >> 4) + (it << 4);
        int io = (t & 15) << 2;
        f32x4 v = *(const f32x4*)&out_t[c * 68 + io];
        f32x4 xv = *(const f32x4*)&xb[((size_t)c << 12) + i0 + io];
        v += xv;
        *(f32x4*)&ob[((size_t)c << 12) + i0 + io] = v;
    }
}

// ---------------------------------------------------------------------------
extern "C" void kernel_launch(void* const* d_in, const int* in_sizes, int n_in,
                              void* d_out, int out_size, void* d_ws, size_t ws_size,
                              hipStream_t stream)
{
    (void)in_sizes; (void)n_in; (void)out_size; (void)ws_size;
    const float* x = (const float*)d_in[0];
    const float* wq = (const float*)d_in[1];
    const float* qg = (const float*)d_in[2];
    const float* qb = (const float*)d_in[3];
    const float* qm = (const float*)d_in[4];
    const float* qv = (const float*)d_in[5];
    const float* wk = (const float*)d_in[6];
    const float* kg = (const float*)d_in[7];
    const float* kb = (const float*)d_in[8];
    const float* km = (const float*)d_in[9];
    const float* kv = (const float*)d_in[10];
    const float* wv = (const float*)d_in[11];
    const float* vg = (const float*)d_in[12];
    const float* vb = (const float*)d_in[13];
    const float* vm = (const float*)d_in[14];
    const float* vv = (const float*)d_in[15];
    const float* gamma = (const float*)d_in[16];

    // workspace: q_hi|q_lo|k_hi|k_lo: 4 x [B][N][32] bf16 (1MB each), v: [B][256][N] bf16 (8MB)
    unsigned short* ws = (unsigned short*)d_ws;
    const size_t QK = (size_t)NB * NN * 32;       // 524288 elements
    unsigned short* qhi = ws;
    unsigned short* qlo = ws + QK;
    unsigned short* khi = ws + 2 * QK;
    unsigned short* klo = ws + 3 * QK;
    unsigned short* vws = ws + 4 * QK;            // 4194304 elements

    proj_kernel<<<dim3(512), dim3(256), 0, stream>>>(
        x, wq, qg, qb, qm, qv, wk, kg, kb, km, kv, wv, vg, vb, vm, vv,
        qhi, qlo, khi, klo, vws);
    attn_kernel<<<dim3(256), dim3(256), 0, stream>>>(
        x, gamma, qhi, qlo, khi, klo, vws, (float*)d_out);
}

// Round 2
// 205.747 us; speedup vs baseline: 1.4612x; 1.4612x over previous
//
#include <hip/hip_runtime.h>
#include <stdint.h>

// Problem constants (B=4, C=256, C8=32, H=W=64, N=4096)
#define NB 4
#define NC 256
#define NC8 32
#define NN 4096

typedef __attribute__((ext_vector_type(8))) short bf16x8;
typedef __attribute__((ext_vector_type(4))) float f32x4;
typedef __attribute__((ext_vector_type(8))) unsigned short u16x8;
typedef __attribute__((ext_vector_type(4))) unsigned short u16x4;

#define MFMA16(a, b, c) __builtin_amdgcn_mfma_f32_16x16x32_bf16((a), (b), (c), 0, 0, 0)
#define LOG2E 1.4426950408889634f

__device__ __forceinline__ unsigned short bf16_rne(float f) {
    unsigned int u = __builtin_bit_cast(unsigned int, f);
    u += 0x7fffu + ((u >> 16) & 1u);
    return (unsigned short)(u >> 16);
}
__device__ __forceinline__ float bf16_to_f(unsigned short h) {
    return __builtin_bit_cast(float, (unsigned int)h << 16);
}
__device__ __forceinline__ float exp2_hw(float x) {
    float r;
    asm("v_exp_f32 %0, %1" : "=v"(r) : "v"(x));
    return r;
}

template <int CTRL>
__device__ __forceinline__ float dpp_mov_f(float v) {
    return __builtin_bit_cast(float,
        __builtin_amdgcn_update_dpp(0, __builtin_bit_cast(int, v), CTRL, 0xf, 0xf, false));
}
// reduce across the 16-lane DPP row (all lanes end with the result)
__device__ __forceinline__ float rowmax16(float v) {
    v = fmaxf(v, dpp_mov_f<0x128>(v));  // row_ror:8
    v = fmaxf(v, dpp_mov_f<0x124>(v));  // row_ror:4
    v = fmaxf(v, dpp_mov_f<0x122>(v));  // row_ror:2
    v = fmaxf(v, dpp_mov_f<0x121>(v));  // row_ror:1
    return v;
}
__device__ __forceinline__ float rowsum16(float v) {
    v += dpp_mov_f<0x128>(v);
    v += dpp_mov_f<0x124>(v);
    v += dpp_mov_f<0x122>(v);
    v += dpp_mov_f<0x121>(v);
    return v;
}

__device__ __forceinline__ void async16(const void* g, void* l) {
    __builtin_amdgcn_global_load_lds(
        (const __attribute__((address_space(1))) unsigned int*)g,
        (__attribute__((address_space(3))) unsigned int*)l, 16, 0, 0);
}

// ---------------------------------------------------------------------------
// Projection kernel: q,k (fp32 -> bf16 hi/lo split) and v (bf16), BN folded.
// q is additionally scaled by log2(e) so attention softmax can use exp2.
// q_hi/q_lo/k_hi/k_lo layout: [B][N][32] bf16 ; v layout: [B][256][N] bf16.
// Grid: 512 blocks x 256 threads; block handles 32 spatial positions.
// ---------------------------------------------------------------------------
__global__ __launch_bounds__(256) void proj_kernel(
    const float* __restrict__ x,
    const float* __restrict__ wq,
    const float* __restrict__ qg, const float* __restrict__ qb,
    const float* __restrict__ qm, const float* __restrict__ qv,
    const float* __restrict__ wk,
    const float* __restrict__ kg, const float* __restrict__ kb,
    const float* __restrict__ km, const float* __restrict__ kv,
    const float* __restrict__ wv,
    const float* __restrict__ vg, const float* __restrict__ vb,
    const float* __restrict__ vm, const float* __restrict__ vv,
    unsigned short* __restrict__ qhi, unsigned short* __restrict__ qlo,
    unsigned short* __restrict__ khi, unsigned short* __restrict__ klo,
    unsigned short* __restrict__ vws)
{
    __shared__ float xt[NC * 36 + 8];
    const int t = threadIdx.x;
    const int blk = blockIdx.x;
    const int b = blk >> 7;
    const int n0 = (blk & 127) << 5;
    const float* xb = x + ((size_t)b << 20);

    for (int idx = t; idx < NC * 32; idx += 256) {
        int c = idx >> 5, j = idx & 31;
        xt[c * 36 + j] = xb[((size_t)c << 12) + n0 + j];
    }
    __syncthreads();

    // ---- q / k : thread = (p = t&31, og = t>>5); og 0-3 -> q rows o0..o0+7, og 4-7 -> k
    {
        const int p = t & 31;
        const int og = t >> 5;
        const bool is_k = og >= 4;
        const int o0 = (og & 3) << 3;
        const float* w = is_k ? wk : wq;
        float acc[8];
#pragma unroll
        for (int o = 0; o < 8; ++o) acc[o] = 0.f;
        for (int c4 = 0; c4 < NC; c4 += 4) {
            float x0 = xt[(c4 + 0) * 36 + p];
            float x1 = xt[(c4 + 1) * 36 + p];
            float x2 = xt[(c4 + 2) * 36 + p];
            float x3 = xt[(c4 + 3) * 36 + p];
#pragma unroll
            for (int o = 0; o < 8; ++o) {
                const float4 w4 = *(const float4*)&w[(o0 + o) * NC + c4];
                acc[o] += w4.x * x0 + w4.y * x1 + w4.z * x2 + w4.w * x3;
            }
        }
        const float* G = is_k ? kg : qg;
        const float* Bb = is_k ? kb : qb;
        const float* M = is_k ? km : qm;
        const float* V = is_k ? kv : qv;
        u16x8 hv, lv;
#pragma unroll
        for (int o = 0; o < 8; ++o) {
            int oo = o0 + o;
            float sc = G[oo] / sqrtf(V[oo] + 1e-5f);
            float val = acc[o] * sc + (Bb[oo] - M[oo] * sc);
            if (!is_k) val *= LOG2E;   // fold log2(e) into q -> softmax uses exp2
            unsigned short h = bf16_rne(val);
            hv[o] = h;
            lv[o] = bf16_rne(val - bf16_to_f(h));
        }
        size_t base = ((size_t)(b << 12) + n0 + p) * 32 + o0;
        *(u16x8*)&(is_k ? khi : qhi)[base] = hv;
        *(u16x8*)&(is_k ? klo : qlo)[base] = lv;
    }

    // ---- v : thread = (p4 = (t&7)*4, og = t>>3)
    {
        const int p4 = (t & 7) << 2;
        const int og = t >> 3;
        const int o0 = og << 3;
        float acc[4][8];
#pragma unroll
        for (int pp = 0; pp < 4; ++pp)
#pragma unroll
            for (int o = 0; o < 8; ++o) acc[pp][o] = 0.f;
        for (int c4 = 0; c4 < NC; c4 += 4) {
            float4 xv0 = *(const float4*)&xt[(c4 + 0) * 36 + p4];
            float4 xv1 = *(const float4*)&xt[(c4 + 1) * 36 + p4];
            float4 xv2 = *(const float4*)&xt[(c4 + 2) * 36 + p4];
            float4 xv3 = *(const float4*)&xt[(c4 + 3) * 36 + p4];
#pragma unroll
            for (int o = 0; o < 8; ++o) {
                const float4 w4 = *(const float4*)&wv[(o0 + o) * NC + c4];
                acc[0][o] += w4.x * xv0.x + w4.y * xv1.x + w4.z * xv2.x + w4.w * xv3.x;
                acc[1][o] += w4.x * xv0.y + w4.y * xv1.y + w4.z * xv2.y + w4.w * xv3.y;
                acc[2][o] += w4.x * xv0.z + w4.y * xv1.z + w4.z * xv2.z + w4.w * xv3.z;
                acc[3][o] += w4.x * xv0.w + w4.y * xv1.w + w4.z * xv2.w + w4.w * xv3.w;
            }
        }
#pragma unroll
        for (int o = 0; o < 8; ++o) {
            int oo = o0 + o;
            float sc = vg[oo] / sqrtf(vv[oo] + 1e-5f);
            float sh = vb[oo] - vm[oo] * sc;
            u16x4 st;
#pragma unroll
            for (int pp = 0; pp < 4; ++pp) st[pp] = bf16_rne(acc[pp][o] * sc + sh);
            *(u16x4*)&vws[((size_t)(b * NC + oo) << 12) + n0 + p4] = st;
        }
    }
}

// ---------------------------------------------------------------------------
// Flash attention kernel v2.
// Grid: 512 blocks x 256 threads (4 waves). Block = 32 q-rows x all 256 c.
// Wave (wi,wc): rows i0+wi*16..+15, cols wc*128..+127 (1 i-frag x 8 c-frags).
// LDS: 2 x 20KB staged {Khi 2K | Klo 2K | V 16K} (XOR-swizzled via pre-swizzled
// global source), 4 x 1KB per-wave P. Epilogue reuses 32KB as transpose buf.
// XCD-aware block mapping: xcd pair <-> batch, so K/V (2.5MB) stays in one L2.
// ---------------------------------------------------------------------------
__global__ __launch_bounds__(256, 3) void attn_kernel(
    const float* __restrict__ x, const float* __restrict__ gamma_p,
    const unsigned short* __restrict__ qhi, const unsigned short* __restrict__ qlo,
    const unsigned short* __restrict__ khi, const unsigned short* __restrict__ klo,
    const unsigned short* __restrict__ vws,
    float* __restrict__ out)
{
    __shared__ __align__(16) char smem[45056];
    const int t = threadIdx.x;
    const int pb = blockIdx.x;
    const int xcd = pb & 7;
    const int b = xcd >> 1;                       // 2 XCDs per batch
    const int tile = ((xcd & 1) << 6) + (pb >> 3);
    const int i0 = tile << 5;                     // 32 rows per block
    const int w = t >> 6, lane = t & 63;
    const int g = lane >> 4, r = lane & 15;
    const int wi = w >> 1, wc = w & 1;

    const size_t bN32 = (size_t)b * (NN * 32);
    const unsigned short* kh_g = khi + bN32;
    const unsigned short* kl_g = klo + bN32;
    const unsigned short* v_g = vws + (size_t)b * (NC * NN);

    // Q fragment (A-operand): lane (g,r) holds row i0+wi*16+r, k-dims g*8..+7
    bf16x8 qh, ql;
    {
        size_t off = bN32 + (size_t)(i0 + wi * 16 + r) * 32 + g * 8;
        qh = *(const bf16x8*)&qhi[off];
        ql = *(const bf16x8*)&qlo[off];
    }

    f32x4 acc[8];
#pragma unroll
    for (int fc = 0; fc < 8; ++fc) acc[fc] = (f32x4){0.f, 0.f, 0.f, 0.f};
    float m_run[4], l_part[4];
#pragma unroll
    for (int e = 0; e < 4; ++e) { m_run[e] = -3.0e38f; l_part[e] = 0.f; }

    // stage one 32-j tile (20 chunks of 1KB) into buffer buf.
    // LDS dest is linear (global_load_lds); the XOR swizzle is applied by
    // permuting the per-lane GLOBAL source column group.
    auto stage = [&](int jt, int buf) {
        char* base = smem + buf * 20480;
        const int j0 = jt << 5;
#pragma unroll
        for (int ci = 0; ci < 5; ++ci) {
            const int cidx = w + ci * 4;
            const unsigned short* gs;
            if (cidx < 4) {   // K hi (0,1) / K lo (2,3), 16 rows per chunk
                int row = ((cidx & 1) << 4) + (lane >> 2);
                int gl = (lane & 3) ^ ((row >> 1) & 3);
                gs = (cidx < 2 ? kh_g : kl_g) + (size_t)(j0 + row) * 32 + (gl << 3);
            } else {          // V: chunk kk covers c rows kk*16..+15
                int c = ((cidx - 4) << 4) + (lane >> 2);
                int gl = (lane & 3) ^ ((c >> 1) & 3);
                gs = v_g + ((size_t)c << 12) + j0 + (gl << 3);
            }
            async16(gs, base + cidx * 1024);
        }
    };

    stage(0, 0);
    __syncthreads();

    for (int jt = 0; jt < NN / 32; ++jt) {
        const int buf = jt & 1;
        if (jt < NN / 32 - 1) stage(jt + 1, buf ^ 1);

        const char* base = smem + buf * 20480;
        const unsigned short* Kh = (const unsigned short*)(base);
        const unsigned short* Kl = (const unsigned short*)(base + 2048);
        const unsigned short* Vl = (const unsigned short*)(base + 4096);

        // ---- S = Q K^T (hi/lo split, fp32 acc, log2 domain) ----
        bf16x8 kfh[2], kfl[2];
#pragma unroll
        for (int fj = 0; fj < 2; ++fj) {
            int row = fj * 16 + r;
            int off = (row << 5) + ((g ^ ((row >> 1) & 3)) << 3);
            kfh[fj] = *(const bf16x8*)&Kh[off];
            kfl[fj] = *(const bf16x8*)&Kl[off];
        }
        f32x4 s[2];
#pragma unroll
        for (int fj = 0; fj < 2; ++fj) {
            f32x4 z = (f32x4){0.f, 0.f, 0.f, 0.f};
            z = MFMA16(qh, kfl[fj], z);
            z = MFMA16(ql, kfh[fj], z);
            z = MFMA16(qh, kfh[fj], z);
            s[fj] = z;
        }

        // ---- online softmax (log2 domain; rows live in 16-lane DPP rows) ----
        float tm[4];
#pragma unroll
        for (int e = 0; e < 4; ++e) tm[e] = rowmax16(fmaxf(s[0][e], s[1][e]));

        bool okf = true;
#pragma unroll
        for (int e = 0; e < 4; ++e) okf = okf && (tm[e] <= m_run[e] + 11.0f);
        if (!__all(okf)) {
            float rs[4];
#pragma unroll
            for (int e = 0; e < 4; ++e) {
                float nm = fmaxf(m_run[e], tm[e]);
                rs[e] = exp2_hw(m_run[e] - nm);
                m_run[e] = nm;
                l_part[e] *= rs[e];
            }
#pragma unroll
            for (int fc = 0; fc < 8; ++fc)
#pragma unroll
                for (int e = 0; e < 4; ++e) acc[fc][e] *= rs[e];
        }

        float p[2][4];
#pragma unroll
        for (int fj = 0; fj < 2; ++fj)
#pragma unroll
            for (int e = 0; e < 4; ++e)
                p[fj][e] = exp2_hw(s[fj][e] - m_run[e]);
#pragma unroll
        for (int e = 0; e < 4; ++e) l_part[e] += p[0][e] + p[1][e];

        // ---- P: D-frag -> bf16 -> per-wave LDS [16][32], colgroup XOR g ----
        unsigned short* P = (unsigned short*)(smem + 40960 + (w << 10));
#pragma unroll
        for (int fj = 0; fj < 2; ++fj)
#pragma unroll
            for (int e = 0; e < 4; ++e)
                P[((g * 4 + e) << 5) + (((fj * 2 + (r >> 3)) ^ g) << 3) + (r & 7)] =
                    bf16_rne(p[fj][e]);
        asm volatile("s_waitcnt lgkmcnt(0)" ::: "memory");
        __builtin_amdgcn_sched_barrier(0);

        // ---- PV: acc += P[16x32] * V[32x16 per c-frag] ----
        bf16x8 pa = *(const bf16x8*)&P[(r << 5) + ((g ^ (r >> 2)) << 3)];
#pragma unroll
        for (int fc = 0; fc < 8; ++fc) {
            int c = (wc << 7) + (fc << 4) + r;
            bf16x8 vbf = *(const bf16x8*)&Vl[(c << 5) + ((g ^ ((c >> 1) & 3)) << 3)];
            acc[fc] = MFMA16(pa, vbf, acc[fc]);
        }
        __syncthreads();  // drains stage(jt+1) vmcnt + protects buffer swap
    }

    // ---- epilogue: out = gamma * acc/l + x, transpose through swizzled LDS ----
    const float gm = gamma_p[0];
    float linv[4];
#pragma unroll
    for (int e = 0; e < 4; ++e) linv[e] = gm / rowsum16(l_part[e]);

    // write acc into [c 0..255][i 0..31] f32, i-slot (16B) XOR (c&7)
    char* ep = smem;
#pragma unroll
    for (int fc = 0; fc < 8; ++fc) {
        int c = (wc << 7) + (fc << 4) + r;
        int islot = wi * 4 + g;
        float* dst = (float*)(ep + (c << 7) + (((islot ^ (c & 7)) << 4)));
#pragma unroll
        for (int e = 0; e < 4; ++e) dst[e] = acc[fc][e] * linv[e];
    }
    __syncthreads();

    const float* xb = x + ((size_t)b << 20);
    float* ob = out + ((size_t)b << 20);
#pragma unroll
    for (int it = 0; it < 8; ++it) {
        int c = (t >> 3) + (it << 5);
        int j = t & 7;
        int islot = j ^ (c & 7);
        f32x4 v = *(const f32x4*)(ep + (c << 7) + (j << 4));
        f32x4 xv = *(const f32x4*)&xb[((size_t)c << 12) + i0 + islot * 4];
        v += xv;
        *(f32x4*)&ob[((size_t)c << 12) + i0 + islot * 4] = v;
    }
}

// ---------------------------------------------------------------------------
extern "C" void kernel_launch(void* const* d_in, const int* in_sizes, int n_in,
                              void* d_out, int out_size, void* d_ws, size_t ws_size,
                              hipStream_t stream)
{
    (void)in_sizes; (void)n_in; (void)out_size; (void)ws_size;
    const float* x = (const float*)d_in[0];
    const float* wq = (const float*)d_in[1];
    const float* qg = (const float*)d_in[2];
    const float* qb = (const float*)d_in[3];
    const float* qm = (const float*)d_in[4];
    const float* qv = (const float*)d_in[5];
    const float* wk = (const float*)d_in[6];
    const float* kg = (const float*)d_in[7];
    const float* kb = (const float*)d_in[8];
    const float* km = (const float*)d_in[9];
    const float* kv = (const float*)d_in[10];
    const float* wv = (const float*)d_in[11];
    const float* vg = (const float*)d_in[12];
    const float* vb = (const float*)d_in[13];
    const float* vm = (const float*)d_in[14];
    const float* vv = (const float*)d_in[15];
    const float* gamma = (const float*)d_in[16];

    unsigned short* ws = (unsigned short*)d_ws;
    const size_t QK = (size_t)NB * NN * 32;
    unsigned short* qhi = ws;
    unsigned short* qlo = ws + QK;
    unsigned short* khi = ws + 2 * QK;
    unsigned short* klo = ws + 3 * QK;
    unsigned short* vws = ws + 4 * QK;

    proj_kernel<<<dim3(512), dim3(256), 0, stream>>>(
        x, wq, qg, qb, qm, qv, wk, kg, kb, km, kv, wv, vg, vb, vm, vv,
        qhi, qlo, khi, klo, vws);
    attn_kernel<<<dim3(512), dim3(256), 0, stream>>>(
        x, gamma, qhi, qlo, khi, klo, vws, (float*)d_out);
}